// Round 1
// baseline (278.275 us; speedup 1.0000x reference)
//
#include <hip/hip_runtime.h>

// DiceLoss: predict,target fp32 [B=2, O=4, D=64, H=256, W=256]
// out = mean over (b,o) of [ sum_d valid*(1 - 2*num/den) / sum_d valid ]
// num = sum_hw sigmoid(p)*t ; den = sum_hw sigmoid(p) + sum_hw t + 1
// valid = (t[b,o,d,0] != -1)

constexpr int HW       = 256 * 256;        // 65536 floats per slice
constexpr int NSLICE   = 2 * 4 * 64;       // 512 slices
constexpr int NPAIR    = 2 * 4;            // 8 (b,o) pairs
constexpr int CHUNKS   = 4;                // chunks per slice
constexpr int NBLOCK   = NSLICE * CHUNKS;  // 2048 blocks
constexpr int THREADS  = 256;
constexpr int CHUNK_F4 = HW / 4 / CHUNKS;  // 4096 float4 per chunk
constexpr int ITERS    = CHUNK_F4 / THREADS; // 16 float4 per thread per array
constexpr int BATCH    = 8;
constexpr int OUTER    = ITERS / BATCH;    // 2

// Workspace layout (floats): ws[0..2047]=sum(sig*t), ws[2048..4095]=sum(sig),
// ws[4096..6143]=sum(t). Total 24 KB.

__global__ __launch_bounds__(THREADS, 2) void dice_stage1(
    const float* __restrict__ predict,
    const float* __restrict__ target,
    float* __restrict__ ws)
{
    const int blk = blockIdx.x;           // = slice*4 + chunk (contiguous tiling)
    const int tid = threadIdx.x;
    const size_t base4 = (size_t)blk * CHUNK_F4;
    const float4* __restrict__ p4 = (const float4*)predict + base4;
    const float4* __restrict__ t4 = (const float4*)target  + base4;

    float s_pt0 = 0.f, s_pt1 = 0.f, s_p0 = 0.f, s_p1 = 0.f, s_t0 = 0.f, s_t1 = 0.f;

    for (int it = 0; it < OUTER; ++it) {
        float4 pv[BATCH], tv[BATCH];
        // Issue all 16 loads (16 KB/wave in flight) ...
#pragma unroll
        for (int j = 0; j < BATCH; ++j)
            pv[j] = p4[(it * BATCH + j) * THREADS + tid];
#pragma unroll
        for (int j = 0; j < BATCH; ++j)
            tv[j] = t4[(it * BATCH + j) * THREADS + tid];
        // ... and forbid the scheduler from sinking any of them into the
        // consumption chain (the previous version collapsed to VGPR=32 and
        // ~2 loads in flight). All VMEM above, all math below.
        __builtin_amdgcn_sched_barrier(0);
#pragma unroll
        for (int j = 0; j < BATCH; ++j) {
            float e0 = 1.f / (1.f + __expf(-pv[j].x));
            float e1 = 1.f / (1.f + __expf(-pv[j].y));
            float e2 = 1.f / (1.f + __expf(-pv[j].z));
            float e3 = 1.f / (1.f + __expf(-pv[j].w));
            s_pt0 += e0 * tv[j].x + e1 * tv[j].y;
            s_pt1 += e2 * tv[j].z + e3 * tv[j].w;
            s_p0  += e0 + e1;
            s_p1  += e2 + e3;
            s_t0  += tv[j].x + tv[j].y;
            s_t1  += tv[j].z + tv[j].w;
        }
    }

    float s_pt = s_pt0 + s_pt1;
    float s_p  = s_p0 + s_p1;
    float s_t  = s_t0 + s_t1;

    // wave (64-lane) shuffle reduction
#pragma unroll
    for (int off = 32; off > 0; off >>= 1) {
        s_pt += __shfl_down(s_pt, off, 64);
        s_p  += __shfl_down(s_p,  off, 64);
        s_t  += __shfl_down(s_t,  off, 64);
    }

    __shared__ float l_pt[THREADS / 64];
    __shared__ float l_p [THREADS / 64];
    __shared__ float l_t [THREADS / 64];
    const int wave = tid >> 6;
    const int lane = tid & 63;
    if (lane == 0) { l_pt[wave] = s_pt; l_p[wave] = s_p; l_t[wave] = s_t; }
    __syncthreads();

    if (tid == 0) {
        float pt = 0.f, sp = 0.f, st = 0.f;
#pragma unroll
        for (int w = 0; w < THREADS / 64; ++w) {
            pt += l_pt[w]; sp += l_p[w]; st += l_t[w];
        }
        ws[blk]              = pt;
        ws[NBLOCK + blk]     = sp;
        ws[2 * NBLOCK + blk] = st;
    }
}

__global__ __launch_bounds__(NSLICE) void dice_stage2(
    const float* __restrict__ ws,
    const float* __restrict__ target,
    float* __restrict__ out)
{
    const int tid = threadIdx.x;          // 0..511 = slice id; wave w = (b,o) pair
    float pt = 0.f, sp = 0.f, st = 0.f;
#pragma unroll
    for (int c = 0; c < CHUNKS; ++c) {
        const int i = tid * CHUNKS + c;
        pt += ws[i];
        sp += ws[NBLOCK + i];
        st += ws[2 * NBLOCK + i];
    }
    const float valid = (target[(size_t)tid * HW] != -1.0f) ? 1.0f : 0.0f;
    const float den   = sp + st + 1.0f;                 // SMOOTH = 1
    const float dice  = 1.0f - 2.0f * pt / den;

    float dv = dice * valid;
    float v  = valid;
#pragma unroll
    for (int off = 32; off > 0; off >>= 1) {
        dv += __shfl_down(dv, off, 64);
        v  += __shfl_down(v,  off, 64);
    }
    __shared__ float pair_avg[NPAIR];
    const int wave = tid >> 6;
    const int lane = tid & 63;
    if (lane == 0) pair_avg[wave] = dv / v;
    __syncthreads();
    if (tid == 0) {
        float s = 0.f;
#pragma unroll
        for (int w = 0; w < NPAIR; ++w) s += pair_avg[w];
        out[0] = s * (1.0f / NPAIR);
    }
}

extern "C" void kernel_launch(void* const* d_in, const int* in_sizes, int n_in,
                              void* d_out, int out_size, void* d_ws, size_t ws_size,
                              hipStream_t stream) {
    const float* predict = (const float*)d_in[0];
    const float* target  = (const float*)d_in[1];
    float* ws  = (float*)d_ws;
    float* out = (float*)d_out;

    dice_stage1<<<NBLOCK, THREADS, 0, stream>>>(predict, target, ws);
    dice_stage2<<<1, NSLICE, 0, stream>>>(ws, target, out);
}